// Round 1
// baseline (754.932 us; speedup 1.0000x reference)
//
#include <hip/hip_runtime.h>

// Flash-attention forward, causal, B=4 H=16 S=2048 D=128, fp32 in/out,
// bf16 MFMA compute (16x16x32). 4 waves/WG, 64 Q-rows/WG, KV-block = 64.
// LDS: K tile [64][128] bf16 (swizzled), V^T tile [128][64] bf16 (swizzled),
// per-wave P tile [16][64] bf16 (swizzled). 40 KB total.

#define SLEN 2048
#define DDIM 128
#define NBH  64
#define QB   64
#define KB   64

typedef __bf16 bf16x8 __attribute__((ext_vector_type(8)));
typedef float  f32x4  __attribute__((ext_vector_type(4)));
typedef unsigned short ushort_t;
typedef ushort_t ushort8 __attribute__((ext_vector_type(8)));

__device__ inline ushort_t f2bf(float f) {
  union { float f; unsigned u; } v; v.f = f;
  unsigned u = v.u;
  u += 0x7FFFu + ((u >> 16) & 1u);   // RNE, finite inputs only
  return (ushort_t)(u >> 16);
}

__global__ __launch_bounds__(256) void fattn_kernel(
    const float* __restrict__ Q, const float* __restrict__ K,
    const float* __restrict__ V, float* __restrict__ Out) {
  __shared__ ushort_t K_sh[64 * 128];   // [k][d], swizzled
  __shared__ ushort_t V_sh[128 * 64];   // [d][k], swizzled
  __shared__ ushort_t P_sh[4][16 * 64]; // per-wave [q][k], swizzled

  const int tid  = threadIdx.x;
  const int lane = tid & 63;
  const int wv   = tid >> 6;
  const int l16  = lane & 15;
  const int lhi  = lane >> 4;
  const int qblk = blockIdx.x;
  const int bh   = blockIdx.y;

  const float scale = 0.08838834764831845f; // 1/sqrt(128)

  const size_t base = (size_t)bh * SLEN * DDIM;
  const float* Qp = Q + base;
  const float* Kp = K + base;
  const float* Vp = V + base;
  float*       Op = Out + base;

  // ---- load Q fragments (pre-scaled), A-layout: row=l16, k=lhi*8+i ----
  bf16x8 qf[4];
  {
    const int qrow = qblk * QB + wv * 16 + l16;
    const float* qr = Qp + (size_t)qrow * DDIM;
#pragma unroll
    for (int dc = 0; dc < 4; ++dc) {
      int d0 = dc * 32 + lhi * 8;
      float4 x = *reinterpret_cast<const float4*>(qr + d0);
      float4 y = *reinterpret_cast<const float4*>(qr + d0 + 4);
      ushort8 uu;
      uu[0] = f2bf(x.x * scale); uu[1] = f2bf(x.y * scale);
      uu[2] = f2bf(x.z * scale); uu[3] = f2bf(x.w * scale);
      uu[4] = f2bf(y.x * scale); uu[5] = f2bf(y.y * scale);
      uu[6] = f2bf(y.z * scale); uu[7] = f2bf(y.w * scale);
      qf[dc] = __builtin_bit_cast(bf16x8, uu);
    }
  }

  f32x4 Oacc[8];
#pragma unroll
  for (int i = 0; i < 8; ++i) Oacc[i] = (f32x4){0.f, 0.f, 0.f, 0.f};
  float m_run[4], l_run[4];
#pragma unroll
  for (int r = 0; r < 4; ++r) { m_run[r] = -3.0e38f; l_run[r] = 0.f; }

  for (int kb = 0; kb <= qblk; ++kb) {
    __syncthreads();  // previous tile's compute done before restage

    // ---- stage K tile: 64x128 fp32 -> bf16 LDS (swizzled rows) ----
    {
      const float* src = Kp + (size_t)kb * KB * DDIM;
#pragma unroll
      for (int it = 0; it < 8; ++it) {
        int idx4 = it * 256 + tid;       // float4 index, 2048 total
        int r  = idx4 >> 5;              // 32 float4 per row
        int c4 = idx4 & 31;
        float4 x = *reinterpret_cast<const float4*>(src + r * DDIM + c4 * 4);
        unsigned lo = ((unsigned)f2bf(x.y) << 16) | f2bf(x.x);
        unsigned hi = ((unsigned)f2bf(x.w) << 16) | f2bf(x.z);
        int e = (r * 128 + c4 * 4) ^ ((r & 7) << 3);
        *reinterpret_cast<uint2*>(&K_sh[e]) = make_uint2(lo, hi);
      }
      // ---- stage V transposed: V^T[d][k], swizzled ----
      const float* vs = Vp + (size_t)kb * KB * DDIM;
#pragma unroll
      for (int it = 0; it < 8; ++it) {
        int idx4 = it * 256 + tid;
        int r  = idx4 >> 5;              // k row
        int c4 = idx4 & 31;
        float4 x = *reinterpret_cast<const float4*>(vs + r * DDIM + c4 * 4);
        int c0 = c4 * 4;
        float vals[4] = {x.x, x.y, x.z, x.w};
#pragma unroll
        for (int j = 0; j < 4; ++j) {
          int d = c0 + j;
          V_sh[(d * 64 + r) ^ ((d & 7) << 3)] = f2bf(vals[j]);
        }
      }
    }
    __syncthreads();

    // ---- S = Q K^T for this tile: 4 col-groups of 16 ----
    f32x4 sacc[4];
#pragma unroll
    for (int g = 0; g < 4; ++g) {
      f32x4 acc = (f32x4){0.f, 0.f, 0.f, 0.f};
#pragma unroll
      for (int dc = 0; dc < 4; ++dc) {
        int row = g * 16 + l16;
        int e = (row * 128 + dc * 32 + lhi * 8) ^ ((row & 7) << 3);
        bf16x8 kf = *reinterpret_cast<const bf16x8*>(&K_sh[e]);
        acc = __builtin_amdgcn_mfma_f32_16x16x32_bf16(qf[dc], kf, acc, 0, 0, 0);
      }
      sacc[g] = acc;
    }

    // ---- causal mask (diagonal block only) ----
    if (kb == qblk) {
      int qrow0 = wv * 16 + lhi * 4;     // local q within the 64-block
#pragma unroll
      for (int g = 0; g < 4; ++g) {
        int kcol = g * 16 + l16;
#pragma unroll
        for (int r = 0; r < 4; ++r) {
          if (kcol > qrow0 + r) sacc[g][r] = -3.0e38f;
        }
      }
    }

    // ---- online softmax (rows live in 16-lane groups) ----
    float tmax[4];
#pragma unroll
    for (int r = 0; r < 4; ++r)
      tmax[r] = fmaxf(fmaxf(sacc[0][r], sacc[1][r]),
                      fmaxf(sacc[2][r], sacc[3][r]));
#pragma unroll
    for (int x = 1; x < 16; x <<= 1) {
#pragma unroll
      for (int r = 0; r < 4; ++r)
        tmax[r] = fmaxf(tmax[r], __shfl_xor(tmax[r], x));
    }

    float alpha[4], mnew[4];
#pragma unroll
    for (int r = 0; r < 4; ++r) {
      mnew[r]  = fmaxf(m_run[r], tmax[r]);
      alpha[r] = __expf(m_run[r] - mnew[r]);
      m_run[r] = mnew[r];
    }

    float rsum[4] = {0.f, 0.f, 0.f, 0.f};
#pragma unroll
    for (int g = 0; g < 4; ++g) {
#pragma unroll
      for (int r = 0; r < 4; ++r) {
        float p = __expf(sacc[g][r] - mnew[r]);
        rsum[r] += p;
        int prow = lhi * 4 + r;
        P_sh[wv][(prow * 64 + g * 16 + l16) ^ ((prow & 7) << 3)] = f2bf(p);
      }
    }
#pragma unroll
    for (int x = 1; x < 16; x <<= 1) {
#pragma unroll
      for (int r = 0; r < 4; ++r) rsum[r] += __shfl_xor(rsum[r], x);
    }
#pragma unroll
    for (int r = 0; r < 4; ++r) l_run[r] = l_run[r] * alpha[r] + rsum[r];

    // ---- rescale O ----
#pragma unroll
    for (int dg = 0; dg < 8; ++dg)
#pragma unroll
      for (int r = 0; r < 4; ++r) Oacc[dg][r] *= alpha[r];

    // ---- PV: O += P V ----
    bf16x8 pf[2];
#pragma unroll
    for (int kc = 0; kc < 2; ++kc) {
      int e = (l16 * 64 + kc * 32 + lhi * 8) ^ ((l16 & 7) << 3);
      pf[kc] = *reinterpret_cast<const bf16x8*>(&P_sh[wv][e]);
    }
#pragma unroll
    for (int dg = 0; dg < 8; ++dg) {
#pragma unroll
      for (int kc = 0; kc < 2; ++kc) {
        int row = dg * 16 + l16;
        int e = (row * 64 + kc * 32 + lhi * 8) ^ ((row & 7) << 3);
        bf16x8 vf = *reinterpret_cast<const bf16x8*>(&V_sh[e]);
        Oacc[dg] = __builtin_amdgcn_mfma_f32_16x16x32_bf16(pf[kc], vf, Oacc[dg], 0, 0, 0);
      }
    }
  }

  // ---- epilogue: normalize and store fp32 ----
#pragma unroll
  for (int r = 0; r < 4; ++r) {
    float inv = 1.0f / l_run[r];
    int q = qblk * QB + wv * 16 + lhi * 4 + r;
    float* orow = Op + (size_t)q * DDIM;
#pragma unroll
    for (int dg = 0; dg < 8; ++dg)
      orow[dg * 16 + l16] = Oacc[dg][r] * inv;
  }
}

extern "C" void kernel_launch(void* const* d_in, const int* in_sizes, int n_in,
                              void* d_out, int out_size, void* d_ws, size_t ws_size,
                              hipStream_t stream) {
  const float* Q = (const float*)d_in[0];
  const float* K = (const float*)d_in[1];
  const float* V = (const float*)d_in[2];
  // d_in[3] is the causal mask; it is always tril(ones), handled analytically.
  float* O = (float*)d_out;
  dim3 grid(SLEN / QB, NBH);
  fattn_kernel<<<grid, dim3(256), 0, stream>>>(Q, K, V, O);
}

// Round 2
// 350.981 us; speedup vs baseline: 2.1509x; 2.1509x over previous
//
#include <hip/hip_runtime.h>

// Flash-attention forward, causal, B=4 H=16 S=2048 D=128, fp32 in/out.
// Round 2: pre-pass converts K -> bf16 and V -> V^T bf16 in d_ws; main kernel
// stages tiles via global_load_lds (16B) with pre-swizzled global source
// (linear LDS dest + XOR-involution source == XOR on read, rule 21).
// 4 waves/WG, 64 Q-rows/WG, KV-block = 64. LDS 40KB.

#define SLEN 2048
#define DDIM 128
#define NBH  64
#define QB   64
#define KB   64

typedef __bf16 bf16x8 __attribute__((ext_vector_type(8)));
typedef float  f32x4  __attribute__((ext_vector_type(4)));
typedef unsigned short ushort_t;
typedef ushort_t ushort8 __attribute__((ext_vector_type(8)));

__device__ inline ushort_t f2bf(float f) {
  union { float f; unsigned u; } v; v.f = f;
  unsigned u = v.u;
  u += 0x7FFFu + ((u >> 16) & 1u);   // RNE, finite inputs only
  return (ushort_t)(u >> 16);
}

// ---------------- pre-pass: K fp32 -> bf16 (same layout) ----------------
__global__ __launch_bounds__(256) void convert_k_kernel(
    const float* __restrict__ in, ushort_t* __restrict__ out, int n4) {
  int stride = gridDim.x * blockDim.x;
  for (int i = blockIdx.x * blockDim.x + threadIdx.x; i < n4; i += stride) {
    float4 x = reinterpret_cast<const float4*>(in)[i];
    unsigned lo = (unsigned)f2bf(x.x) | ((unsigned)f2bf(x.y) << 16);
    unsigned hi = (unsigned)f2bf(x.z) | ((unsigned)f2bf(x.w) << 16);
    reinterpret_cast<uint2*>(out)[i] = make_uint2(lo, hi);
  }
}

// ------------- pre-pass: V [bh][s][d] fp32 -> Vt [bh][d][s] bf16 -------------
__global__ __launch_bounds__(256) void transpose_v_kernel(
    const float* __restrict__ V, ushort_t* __restrict__ Vt) {
  __shared__ float t[64][33];          // [s_local][d_local]
  const int bh = blockIdx.z;
  const int s0 = blockIdx.x * 64;
  const int d0 = blockIdx.y * 32;
  const int tx = threadIdx.x & 31;
  const int ty = threadIdx.x >> 5;     // 0..7
  const float* src = V + ((size_t)bh * SLEN + s0) * DDIM + d0;
#pragma unroll
  for (int j = 0; j < 8; ++j) {
    int sl = ty + j * 8;
    t[sl][tx] = src[(size_t)sl * DDIM + tx];
  }
  __syncthreads();
  ushort_t* dst = Vt + ((size_t)bh * DDIM + d0) * SLEN + s0;
#pragma unroll
  for (int j = 0; j < 4; ++j) {
    int dl = ty + j * 8;
    unsigned lo = f2bf(t[tx * 2][dl]);
    unsigned hi = f2bf(t[tx * 2 + 1][dl]);
    *reinterpret_cast<unsigned*>(&dst[(size_t)dl * SLEN + tx * 2]) =
        lo | (hi << 16);
  }
}

// ---------------- main kernel (preconverted bf16 K / V^T) ----------------
__global__ __launch_bounds__(256) void fattn2_kernel(
    const float* __restrict__ Q, const ushort_t* __restrict__ Kb,
    const ushort_t* __restrict__ Vt, float* __restrict__ Out) {
  __shared__ ushort_t K_sh[64 * 128];   // [k][d], chunk-swizzled via source
  __shared__ ushort_t V_sh[128 * 64];   // [d][k], chunk-swizzled via source
  __shared__ ushort_t P_sh[4][16 * 64]; // per-wave [q][k], swizzled

  const int tid  = threadIdx.x;
  const int lane = tid & 63;
  const int wv   = tid >> 6;
  const int l16  = lane & 15;
  const int lhi  = lane >> 4;
  const int qblk = (gridDim.x - 1) - blockIdx.x;  // heavy blocks first
  const int bh   = blockIdx.y;

  const float scale = 0.08838834764831845f; // 1/sqrt(128)

  const float*    Qp = Q  + (size_t)bh * SLEN * DDIM;
  const ushort_t* Kp = Kb + (size_t)bh * SLEN * DDIM;
  const ushort_t* Vp = Vt + (size_t)bh * DDIM * SLEN;
  float*          Op = Out + (size_t)bh * SLEN * DDIM;

  // ---- Q fragments (pre-scaled bf16), A-layout: row=l16, k=lhi*8+i ----
  bf16x8 qf[4];
  {
    const int qrow = qblk * QB + wv * 16 + l16;
    const float* qr = Qp + (size_t)qrow * DDIM;
#pragma unroll
    for (int dc = 0; dc < 4; ++dc) {
      int d0 = dc * 32 + lhi * 8;
      float4 x = *reinterpret_cast<const float4*>(qr + d0);
      float4 y = *reinterpret_cast<const float4*>(qr + d0 + 4);
      ushort8 uu;
      uu[0] = f2bf(x.x * scale); uu[1] = f2bf(x.y * scale);
      uu[2] = f2bf(x.z * scale); uu[3] = f2bf(x.w * scale);
      uu[4] = f2bf(y.x * scale); uu[5] = f2bf(y.y * scale);
      uu[6] = f2bf(y.z * scale); uu[7] = f2bf(y.w * scale);
      qf[dc] = __builtin_bit_cast(bf16x8, uu);
    }
  }

  f32x4 Oacc[8];
#pragma unroll
  for (int i = 0; i < 8; ++i) Oacc[i] = (f32x4){0.f, 0.f, 0.f, 0.f};
  float m_run[4], l_run[4];
#pragma unroll
  for (int r = 0; r < 4; ++r) { m_run[r] = -3.0e38f; l_run[r] = 0.f; }

  for (int kb = 0; kb <= qblk; ++kb) {
    __syncthreads();  // previous tile's LDS reads done before restage

    // ---- stage K tile [64][128] bf16 via global_load_lds (src pre-swizzled) ----
    {
      const ushort_t* ksrc = Kp + (size_t)(kb * KB) * DDIM;
#pragma unroll
      for (int i = 0; i < 4; ++i) {
        int kr = wv * 16 + i * 4 + (lane >> 4);       // tile-local k row
        int c  = lane & 15;                           // 16B chunk in row
        const ushort_t* g = ksrc + kr * DDIM + ((c ^ (kr & 7)) * 8);
        ushort_t* l = &K_sh[(wv * 16 + i * 4) * DDIM];// wave-uniform base
        __builtin_amdgcn_global_load_lds(
            (const __attribute__((address_space(1))) unsigned*)g,
            (__attribute__((address_space(3))) unsigned*)l, 16, 0, 0);
      }
      // ---- stage V^T tile [128][64] bf16 ----
      const ushort_t* vsrc = Vp + (size_t)kb * KB;
#pragma unroll
      for (int i = 0; i < 4; ++i) {
        int vr = wv * 32 + i * 8 + (lane >> 3);       // tile-local d row
        int c  = lane & 7;
        const ushort_t* g = vsrc + (size_t)vr * SLEN + ((c ^ (vr & 7)) * 8);
        ushort_t* l = &V_sh[(wv * 32 + i * 8) * 64];
        __builtin_amdgcn_global_load_lds(
            (const __attribute__((address_space(1))) unsigned*)g,
            (__attribute__((address_space(3))) unsigned*)l, 16, 0, 0);
      }
    }
    __syncthreads();  // drains vmcnt(0) + barrier: tiles visible

    // ---- S = Q K^T: 4 col-groups of 16 ----
    f32x4 sacc[4];
#pragma unroll
    for (int g = 0; g < 4; ++g) {
      f32x4 acc = (f32x4){0.f, 0.f, 0.f, 0.f};
#pragma unroll
      for (int dc = 0; dc < 4; ++dc) {
        int row = g * 16 + l16;
        int e = (row * 128 + dc * 32 + lhi * 8) ^ ((row & 7) << 3);
        bf16x8 kf = *reinterpret_cast<const bf16x8*>(&K_sh[e]);
        acc = __builtin_amdgcn_mfma_f32_16x16x32_bf16(qf[dc], kf, acc, 0, 0, 0);
      }
      sacc[g] = acc;
    }

    // ---- causal mask (diagonal block only) ----
    if (kb == qblk) {
      int qrow0 = wv * 16 + lhi * 4;
      (void)qrow0;
      int q0 = lhi * 4;
#pragma unroll
      for (int g = 0; g < 4; ++g) {
        int kcol = g * 16 + l16;
#pragma unroll
        for (int r = 0; r < 4; ++r) {
          if (kcol > wv * 16 + q0 + r) sacc[g][r] = -3.0e38f;
        }
      }
    }

    // ---- online softmax (rows live across 16-lane groups) ----
    float tmax[4];
#pragma unroll
    for (int r = 0; r < 4; ++r)
      tmax[r] = fmaxf(fmaxf(sacc[0][r], sacc[1][r]),
                      fmaxf(sacc[2][r], sacc[3][r]));
#pragma unroll
    for (int x = 1; x < 16; x <<= 1) {
#pragma unroll
      for (int r = 0; r < 4; ++r)
        tmax[r] = fmaxf(tmax[r], __shfl_xor(tmax[r], x));
    }

    float alpha[4], mnew[4];
#pragma unroll
    for (int r = 0; r < 4; ++r) {
      mnew[r]  = fmaxf(m_run[r], tmax[r]);
      alpha[r] = __expf(m_run[r] - mnew[r]);
      m_run[r] = mnew[r];
    }

    float rsum[4] = {0.f, 0.f, 0.f, 0.f};
#pragma unroll
    for (int g = 0; g < 4; ++g) {
#pragma unroll
      for (int r = 0; r < 4; ++r) {
        float p = __expf(sacc[g][r] - mnew[r]);
        rsum[r] += p;
        int prow = lhi * 4 + r;
        P_sh[wv][(prow * 64 + g * 16 + l16) ^ ((prow & 7) << 3)] = f2bf(p);
      }
    }
#pragma unroll
    for (int x = 1; x < 16; x <<= 1) {
#pragma unroll
      for (int r = 0; r < 4; ++r) rsum[r] += __shfl_xor(rsum[r], x);
    }
#pragma unroll
    for (int r = 0; r < 4; ++r) l_run[r] = l_run[r] * alpha[r] + rsum[r];

    // ---- rescale O ----
#pragma unroll
    for (int dg = 0; dg < 8; ++dg)
#pragma unroll
      for (int r = 0; r < 4; ++r) Oacc[dg][r] *= alpha[r];

    // ---- PV: O += P V ----
    bf16x8 pf[2];
#pragma unroll
    for (int kc = 0; kc < 2; ++kc) {
      int e = (l16 * 64 + kc * 32 + lhi * 8) ^ ((l16 & 7) << 3);
      pf[kc] = *reinterpret_cast<const bf16x8*>(&P_sh[wv][e]);
    }
#pragma unroll
    for (int dg = 0; dg < 8; ++dg) {
#pragma unroll
      for (int kc = 0; kc < 2; ++kc) {
        int row = dg * 16 + l16;
        int e = (row * 64 + kc * 32 + lhi * 8) ^ ((row & 7) << 3);
        bf16x8 vf = *reinterpret_cast<const bf16x8*>(&V_sh[e]);
        Oacc[dg] = __builtin_amdgcn_mfma_f32_16x16x32_bf16(pf[kc], vf, Oacc[dg], 0, 0, 0);
      }
    }
  }

  // ---- epilogue ----
#pragma unroll
  for (int r = 0; r < 4; ++r) {
    float inv = 1.0f / l_run[r];
    int q = qblk * QB + wv * 16 + lhi * 4 + r;
    float* orow = Op + (size_t)q * DDIM;
#pragma unroll
    for (int dg = 0; dg < 8; ++dg)
      orow[dg * 16 + l16] = Oacc[dg][r] * inv;
  }
}

// ---------------- fallback (round-1 kernel, used if ws too small) ----------------
__global__ __launch_bounds__(256) void fattn_kernel(
    const float* __restrict__ Q, const float* __restrict__ K,
    const float* __restrict__ V, float* __restrict__ Out) {
  __shared__ ushort_t K_sh[64 * 128];
  __shared__ ushort_t V_sh[128 * 64];
  __shared__ ushort_t P_sh[4][16 * 64];

  const int tid  = threadIdx.x;
  const int lane = tid & 63;
  const int wv   = tid >> 6;
  const int l16  = lane & 15;
  const int lhi  = lane >> 4;
  const int qblk = blockIdx.x;
  const int bh   = blockIdx.y;
  const float scale = 0.08838834764831845f;

  const size_t base = (size_t)bh * SLEN * DDIM;
  const float* Qp = Q + base;
  const float* Kp = K + base;
  const float* Vp = V + base;
  float*       Op = Out + base;

  bf16x8 qf[4];
  {
    const int qrow = qblk * QB + wv * 16 + l16;
    const float* qr = Qp + (size_t)qrow * DDIM;
#pragma unroll
    for (int dc = 0; dc < 4; ++dc) {
      int d0 = dc * 32 + lhi * 8;
      float4 x = *reinterpret_cast<const float4*>(qr + d0);
      float4 y = *reinterpret_cast<const float4*>(qr + d0 + 4);
      ushort8 uu;
      uu[0] = f2bf(x.x * scale); uu[1] = f2bf(x.y * scale);
      uu[2] = f2bf(x.z * scale); uu[3] = f2bf(x.w * scale);
      uu[4] = f2bf(y.x * scale); uu[5] = f2bf(y.y * scale);
      uu[6] = f2bf(y.z * scale); uu[7] = f2bf(y.w * scale);
      qf[dc] = __builtin_bit_cast(bf16x8, uu);
    }
  }

  f32x4 Oacc[8];
#pragma unroll
  for (int i = 0; i < 8; ++i) Oacc[i] = (f32x4){0.f, 0.f, 0.f, 0.f};
  float m_run[4], l_run[4];
#pragma unroll
  for (int r = 0; r < 4; ++r) { m_run[r] = -3.0e38f; l_run[r] = 0.f; }

  for (int kb = 0; kb <= qblk; ++kb) {
    __syncthreads();
    {
      const float* src = Kp + (size_t)kb * KB * DDIM;
#pragma unroll
      for (int it = 0; it < 8; ++it) {
        int idx4 = it * 256 + tid;
        int r  = idx4 >> 5;
        int c4 = idx4 & 31;
        float4 x = *reinterpret_cast<const float4*>(src + r * DDIM + c4 * 4);
        unsigned lo = ((unsigned)f2bf(x.y) << 16) | f2bf(x.x);
        unsigned hi = ((unsigned)f2bf(x.w) << 16) | f2bf(x.z);
        int e = (r * 128 + c4 * 4) ^ ((r & 7) << 3);
        *reinterpret_cast<uint2*>(&K_sh[e]) = make_uint2(lo, hi);
      }
      const float* vs = Vp + (size_t)kb * KB * DDIM;
#pragma unroll
      for (int it = 0; it < 8; ++it) {
        int idx4 = it * 256 + tid;
        int r  = idx4 >> 5;
        int c4 = idx4 & 31;
        float4 x = *reinterpret_cast<const float4*>(vs + r * DDIM + c4 * 4);
        int c0 = c4 * 4;
        float vals[4] = {x.x, x.y, x.z, x.w};
#pragma unroll
        for (int j = 0; j < 4; ++j) {
          int d = c0 + j;
          V_sh[(d * 64 + r) ^ ((d & 7) << 3)] = f2bf(vals[j]);
        }
      }
    }
    __syncthreads();

    f32x4 sacc[4];
#pragma unroll
    for (int g = 0; g < 4; ++g) {
      f32x4 acc = (f32x4){0.f, 0.f, 0.f, 0.f};
#pragma unroll
      for (int dc = 0; dc < 4; ++dc) {
        int row = g * 16 + l16;
        int e = (row * 128 + dc * 32 + lhi * 8) ^ ((row & 7) << 3);
        bf16x8 kf = *reinterpret_cast<const bf16x8*>(&K_sh[e]);
        acc = __builtin_amdgcn_mfma_f32_16x16x32_bf16(qf[dc], kf, acc, 0, 0, 0);
      }
      sacc[g] = acc;
    }

    if (kb == qblk) {
      int q0 = lhi * 4;
#pragma unroll
      for (int g = 0; g < 4; ++g) {
        int kcol = g * 16 + l16;
#pragma unroll
        for (int r = 0; r < 4; ++r) {
          if (kcol > wv * 16 + q0 + r) sacc[g][r] = -3.0e38f;
        }
      }
    }

    float tmax[4];
#pragma unroll
    for (int r = 0; r < 4; ++r)
      tmax[r] = fmaxf(fmaxf(sacc[0][r], sacc[1][r]),
                      fmaxf(sacc[2][r], sacc[3][r]));
#pragma unroll
    for (int x = 1; x < 16; x <<= 1) {
#pragma unroll
      for (int r = 0; r < 4; ++r)
        tmax[r] = fmaxf(tmax[r], __shfl_xor(tmax[r], x));
    }

    float alpha[4], mnew[4];
#pragma unroll
    for (int r = 0; r < 4; ++r) {
      mnew[r]  = fmaxf(m_run[r], tmax[r]);
      alpha[r] = __expf(m_run[r] - mnew[r]);
      m_run[r] = mnew[r];
    }

    float rsum[4] = {0.f, 0.f, 0.f, 0.f};
#pragma unroll
    for (int g = 0; g < 4; ++g) {
#pragma unroll
      for (int r = 0; r < 4; ++r) {
        float p = __expf(sacc[g][r] - mnew[r]);
        rsum[r] += p;
        int prow = lhi * 4 + r;
        P_sh[wv][(prow * 64 + g * 16 + l16) ^ ((prow & 7) << 3)] = f2bf(p);
      }
    }
#pragma unroll
    for (int x = 1; x < 16; x <<= 1) {
#pragma unroll
      for (int r = 0; r < 4; ++r) rsum[r] += __shfl_xor(rsum[r], x);
    }
#pragma unroll
    for (int r = 0; r < 4; ++r) l_run[r] = l_run[r] * alpha[r] + rsum[r];

#pragma unroll
    for (int dg = 0; dg < 8; ++dg)
#pragma unroll
      for (int r = 0; r < 4; ++r) Oacc[dg][r] *= alpha[r];

    bf16x8 pf[2];
#pragma unroll
    for (int kc = 0; kc < 2; ++kc) {
      int e = (l16 * 64 + kc * 32 + lhi * 8) ^ ((l16 & 7) << 3);
      pf[kc] = *reinterpret_cast<const bf16x8*>(&P_sh[wv][e]);
    }
#pragma unroll
    for (int dg = 0; dg < 8; ++dg) {
#pragma unroll
      for (int kc = 0; kc < 2; ++kc) {
        int row = dg * 16 + l16;
        int e = (row * 64 + kc * 32 + lhi * 8) ^ ((row & 7) << 3);
        bf16x8 vf = *reinterpret_cast<const bf16x8*>(&V_sh[e]);
        Oacc[dg] = __builtin_amdgcn_mfma_f32_16x16x32_bf16(pf[kc], vf, Oacc[dg], 0, 0, 0);
      }
    }
  }

#pragma unroll
  for (int r = 0; r < 4; ++r) {
    float inv = 1.0f / l_run[r];
    int q = qblk * QB + wv * 16 + lhi * 4 + r;
    float* orow = Op + (size_t)q * DDIM;
#pragma unroll
    for (int dg = 0; dg < 8; ++dg)
      orow[dg * 16 + l16] = Oacc[dg][r] * inv;
  }
}

extern "C" void kernel_launch(void* const* d_in, const int* in_sizes, int n_in,
                              void* d_out, int out_size, void* d_ws, size_t ws_size,
                              hipStream_t stream) {
  const float* Q = (const float*)d_in[0];
  const float* K = (const float*)d_in[1];
  const float* V = (const float*)d_in[2];
  float* O = (float*)d_out;

  const size_t n_elem = (size_t)NBH * SLEN * DDIM;      // 16,777,216
  const size_t need   = n_elem * 2 * 2;                 // Kb + Vt bf16

  if (ws_size >= need) {
    ushort_t* Kb = (ushort_t*)d_ws;
    ushort_t* Vt = Kb + n_elem;
    convert_k_kernel<<<2048, 256, 0, stream>>>(K, Kb, (int)(n_elem / 4));
    transpose_v_kernel<<<dim3(SLEN / 64, DDIM / 32, NBH), 256, 0, stream>>>(V, Vt);
    fattn2_kernel<<<dim3(SLEN / QB, NBH), dim3(256), 0, stream>>>(Q, Kb, Vt, O);
  } else {
    fattn_kernel<<<dim3(SLEN / QB, NBH), dim3(256), 0, stream>>>(Q, K, V, O);
  }
}

// Round 3
// 149.800 us; speedup vs baseline: 5.0396x; 2.3430x over previous
//
#include <hip/hip_runtime.h>

// Flash-attention forward, causal, B=4 H=16 S=2048 D=128, fp32 in/out.
// Round 3: m214-style 8-wave 32x32 structure.
//   - prepass: K -> bf16, V -> V^T bf16 (d_ws)
//   - main: 8 waves x 32 q-rows (QB=256), KV tile 64.
//     S^T = K·Q^T via mfma_32x32x16_bf16  (lane owns q = lane&31 column)
//     in-register online softmax (31-op row reduce + shfl_xor 32)
//     P -> bf16 fragments via cvt_pk + one dword-pair shfl_xor(32) per k-step
//     O^T = V^T·P^T  (col = q, so alpha/l are lane-uniform)
//     K/V double-buffered LDS (64KB), prefetch issued right after the single
//     per-tile barrier (T3 2-phase), global_load_lds w=16, src pre-swizzled.

#define SLEN 2048
#define DDIM 128
#define NBH  64
#define QB   256
#define KB   64

typedef __bf16 bf16x8 __attribute__((ext_vector_type(8)));
typedef float  f32x16 __attribute__((ext_vector_type(16)));
typedef float  f32x4  __attribute__((ext_vector_type(4)));
typedef unsigned uint32x4 __attribute__((ext_vector_type(4)));
typedef unsigned short ushort_t;
typedef ushort_t ushort8 __attribute__((ext_vector_type(8)));

__device__ inline ushort_t f2bf(float f) {
  union { float f; unsigned u; } v; v.f = f;
  unsigned u = v.u;
  u += 0x7FFFu + ((u >> 16) & 1u);   // RNE, finite inputs only
  return (ushort_t)(u >> 16);
}

__device__ inline unsigned cvtpk_bf16(float lo, float hi) {
  unsigned r;
  asm("v_cvt_pk_bf16_f32 %0, %1, %2" : "=v"(r) : "v"(lo), "v"(hi));
  return r;
}

// ---------------- pre-pass: K fp32 -> bf16 (same layout) ----------------
__global__ __launch_bounds__(256) void convert_k_kernel(
    const float* __restrict__ in, ushort_t* __restrict__ out, int n4) {
  int stride = gridDim.x * blockDim.x;
  for (int i = blockIdx.x * blockDim.x + threadIdx.x; i < n4; i += stride) {
    float4 x = reinterpret_cast<const float4*>(in)[i];
    unsigned lo = (unsigned)f2bf(x.x) | ((unsigned)f2bf(x.y) << 16);
    unsigned hi = (unsigned)f2bf(x.z) | ((unsigned)f2bf(x.w) << 16);
    reinterpret_cast<uint2*>(out)[i] = make_uint2(lo, hi);
  }
}

// ------------- pre-pass: V [bh][s][d] fp32 -> Vt [bh][d][s] bf16 -------------
__global__ __launch_bounds__(256) void transpose_v_kernel(
    const float* __restrict__ V, ushort_t* __restrict__ Vt) {
  __shared__ float t[64][33];
  const int bh = blockIdx.z;
  const int s0 = blockIdx.x * 64;
  const int d0 = blockIdx.y * 32;
  const int tx = threadIdx.x & 31;
  const int ty = threadIdx.x >> 5;
  const float* src = V + ((size_t)bh * SLEN + s0) * DDIM + d0;
#pragma unroll
  for (int j = 0; j < 8; ++j) {
    int sl = ty + j * 8;
    t[sl][tx] = src[(size_t)sl * DDIM + tx];
  }
  __syncthreads();
  ushort_t* dst = Vt + ((size_t)bh * DDIM + d0) * SLEN + s0;
#pragma unroll
  for (int j = 0; j < 4; ++j) {
    int dl = ty + j * 8;
    unsigned lo = f2bf(t[tx * 2][dl]);
    unsigned hi = f2bf(t[tx * 2 + 1][dl]);
    *reinterpret_cast<unsigned*>(&dst[(size_t)dl * SLEN + tx * 2]) =
        lo | (hi << 16);
  }
}

// ---------------- main kernel: 8 waves, 32x32 MFMA ----------------
__global__ __launch_bounds__(512, 2) void fattn3_kernel(
    const float* __restrict__ Q, const ushort_t* __restrict__ Kb,
    const ushort_t* __restrict__ Vt, float* __restrict__ Out) {
  __shared__ ushort_t K_sh[2][KB * DDIM];   // [buf][k][d]  16KB each
  __shared__ ushort_t V_sh[2][DDIM * KB];   // [buf][d][k]  16KB each

  const int tid  = threadIdx.x;
  const int lane = tid & 63;
  const int wv   = tid >> 6;         // 0..7
  const int l31  = lane & 31;
  const int hi   = lane >> 5;        // 0/1
  // heavy/light pairing: every CU's two WGs sum to exactly 36 tile-units
  const int qblk = (blockIdx.y >= 32) ? blockIdx.x : (7 - (int)blockIdx.x);
  const int bh   = blockIdx.y;

  const float scale = 0.08838834764831845f;  // 1/sqrt(128)

  const float*    Qp = Q  + (size_t)bh * SLEN * DDIM;
  const ushort_t* Kp = Kb + (size_t)bh * SLEN * DDIM;
  const ushort_t* Vp = Vt + (size_t)bh * DDIM * SLEN;
  float*          Op = Out + (size_t)bh * SLEN * DDIM;

  const int q0w = qblk * QB + wv * 32;   // wave's first q row
  const int qg  = q0w + l31;             // this lane's q row

  // ---- Q fragments: B-operand of S^T = K·Q^T. B[d=hi*8+i+16*ds][q=l31] ----
  bf16x8 qf[8];
  {
    const float* qr = Qp + (size_t)qg * DDIM;
#pragma unroll
    for (int ds = 0; ds < 8; ++ds) {
      int d0 = ds * 16 + hi * 8;
      float4 x = *reinterpret_cast<const float4*>(qr + d0);
      float4 y = *reinterpret_cast<const float4*>(qr + d0 + 4);
      ushort8 uu;
      uu[0] = f2bf(x.x * scale); uu[1] = f2bf(x.y * scale);
      uu[2] = f2bf(x.z * scale); uu[3] = f2bf(x.w * scale);
      uu[4] = f2bf(y.x * scale); uu[5] = f2bf(y.y * scale);
      uu[6] = f2bf(y.z * scale); uu[7] = f2bf(y.w * scale);
      qf[ds] = __builtin_bit_cast(bf16x8, uu);
    }
  }

  f32x16 Oacc[4];   // O^T tiles: row=d_local (reg-mapped), col=q (lane-local)
#pragma unroll
  for (int dt = 0; dt < 4; ++dt)
#pragma unroll
    for (int r = 0; r < 16; ++r) Oacc[dt][r] = 0.f;
  float m_run = -3.0e38f, l_run = 0.f;

  const int last_kb      = qblk * 4 + 3;         // WG-uniform tile count
  const int last_kb_wave = (q0w + 31) >> 6;      // beyond: wave skips compute

  auto stage = [&](int buf, int kb) {
    const ushort_t* ksrc = Kp + (size_t)kb * KB * DDIM;
#pragma unroll
    for (int j = 0; j < 2; ++j) {
      int chunk = wv * 128 + j * 64 + lane;      // 16B chunk id, 1024 total
      int row = chunk >> 4, c = chunk & 15;
      const ushort_t* g = ksrc + row * DDIM + ((c ^ (row & 7)) << 3);
      ushort_t* l = &K_sh[buf][(size_t)(wv * 128 + j * 64) * 8];
      __builtin_amdgcn_global_load_lds(
          (const __attribute__((address_space(1))) unsigned*)g,
          (__attribute__((address_space(3))) unsigned*)l, 16, 0, 0);
    }
    const ushort_t* vsrc = Vp + (size_t)kb * KB;
#pragma unroll
    for (int j = 0; j < 2; ++j) {
      int chunk = wv * 128 + j * 64 + lane;      // 1024 chunks of V^T tile
      int row = chunk >> 3, c = chunk & 7;
      const ushort_t* g = vsrc + (size_t)row * SLEN + ((c ^ (row & 7)) << 3);
      ushort_t* l = &V_sh[buf][(size_t)(wv * 128 + j * 64) * 8];
      __builtin_amdgcn_global_load_lds(
          (const __attribute__((address_space(1))) unsigned*)g,
          (__attribute__((address_space(3))) unsigned*)l, 16, 0, 0);
    }
  };

  stage(0, 0);

  for (int kb = 0; kb <= last_kb; ++kb) {
    __syncthreads();                 // drains vmcnt: tile kb resident
    if (kb < last_kb) stage((kb + 1) & 1, kb + 1);  // in flight under compute

    if (kb <= last_kb_wave) {
      const int buf = kb & 1;

      // ---- S^T = K·Q^T : C col = q (lane-local), row = key ----
      f32x16 sac[2];
#pragma unroll
      for (int mt = 0; mt < 2; ++mt) {
        f32x16 a;
#pragma unroll
        for (int r = 0; r < 16; ++r) a[r] = 0.f;
        int row = mt * 32 + l31;
        int sw = row & 7;
#pragma unroll
        for (int ds = 0; ds < 8; ++ds) {
          int c = ds * 2 + hi;
          bf16x8 kf = *reinterpret_cast<const bf16x8*>(
              &K_sh[buf][row * DDIM + ((c ^ sw) << 3)]);
          a = __builtin_amdgcn_mfma_f32_32x32x16_bf16(kf, qf[ds], a, 0, 0, 0);
        }
        sac[mt] = a;
      }

      // ---- causal mask (only tiles that can cross the diagonal) ----
      if (kb * 64 + 63 > q0w) {
#pragma unroll
        for (int mt = 0; mt < 2; ++mt) {
          int kbase = kb * 64 + mt * 32 + 4 * hi;
#pragma unroll
          for (int r = 0; r < 16; ++r) {
            int krow = (r & 3) + 8 * (r >> 2);
            if (kbase + krow > qg) sac[mt][r] = -3.0e38f;
          }
        }
      }

      // ---- online softmax (row = this lane's q; partner holds other half) --
      float tm = sac[0][0];
#pragma unroll
      for (int r = 1; r < 16; ++r) tm = fmaxf(tm, sac[0][r]);
#pragma unroll
      for (int r = 0; r < 16; ++r) tm = fmaxf(tm, sac[1][r]);
      tm = fmaxf(tm, __shfl_xor(tm, 32));

      if (!__all(tm <= m_run)) {
        float mnew  = fmaxf(m_run, tm);
        float alpha = __expf(m_run - mnew);
        m_run = mnew;
        l_run *= alpha;
#pragma unroll
        for (int dt = 0; dt < 4; ++dt)
#pragma unroll
          for (int r = 0; r < 16; ++r) Oacc[dt][r] *= alpha;
      }

      float rs = 0.f;
#pragma unroll
      for (int mt = 0; mt < 2; ++mt)
#pragma unroll
        for (int r = 0; r < 16; ++r) {
          float p = __expf(sac[mt][r] - m_run);
          sac[mt][r] = p;
          rs += p;
        }
      rs += __shfl_xor(rs, 32);
      l_run += rs;

      // ---- P^T fragments for PV: B[k=key=hi*8+i+16*ks][q=l31] ----
      uint32x4 pw[4];
#pragma unroll
      for (int ks = 0; ks < 4; ++ks) {
        const int mt = ks >> 1;
        const int hb = 4 * 2 * (ks & 1);          // reg base of h = 2*(ks&1)
        unsigned pk_h0_0 = cvtpk_bf16(sac[mt][hb + 0], sac[mt][hb + 1]);
        unsigned pk_h0_1 = cvtpk_bf16(sac[mt][hb + 2], sac[mt][hb + 3]);
        unsigned pk_h1_0 = cvtpk_bf16(sac[mt][hb + 4], sac[mt][hb + 5]);
        unsigned pk_h1_1 = cvtpk_bf16(sac[mt][hb + 6], sac[mt][hb + 7]);
        unsigned s0 = hi ? pk_h1_0 : pk_h0_0;
        unsigned s1 = hi ? pk_h1_1 : pk_h0_1;
        unsigned t0 = hi ? pk_h0_0 : pk_h1_0;     // what partner needs
        unsigned t1 = hi ? pk_h0_1 : pk_h1_1;
        unsigned r0 = __shfl_xor(t0, 32);
        unsigned r1 = __shfl_xor(t1, 32);
        uint32x4 f;
        f.x = hi ? r0 : s0;
        f.y = hi ? r1 : s1;
        f.z = hi ? s0 : r0;
        f.w = hi ? s1 : r1;
        pw[ks] = f;
      }

      // ---- O^T += V^T · P^T : A=V^T (m=d), B=P^T (n=q) ----
#pragma unroll
      for (int dt = 0; dt < 4; ++dt) {
        int row = dt * 32 + l31;
        int sw = row & 7;
#pragma unroll
        for (int ks = 0; ks < 4; ++ks) {
          int c = ks * 2 + hi;
          bf16x8 vf = *reinterpret_cast<const bf16x8*>(
              &V_sh[buf][row * 64 + ((c ^ sw) << 3)]);
          Oacc[dt] = __builtin_amdgcn_mfma_f32_32x32x16_bf16(
              vf, __builtin_bit_cast(bf16x8, pw[ks]), Oacc[dt], 0, 0, 0);
        }
      }
    }
  }

  // ---- epilogue: O[q][d] = O^T normalized ----
  {
    float invl = 1.0f / l_run;
    float* orow = Op + (size_t)qg * DDIM;
#pragma unroll
    for (int dt = 0; dt < 4; ++dt)
#pragma unroll
      for (int r = 0; r < 16; ++r) {
        int d = dt * 32 + (r & 3) + 8 * (r >> 2) + 4 * hi;
        orow[d] = Oacc[dt][r] * invl;
      }
  }
}

// ---------------- fallback (round-1 fp32-direct kernel) ----------------
__global__ __launch_bounds__(256) void fattn_kernel(
    const float* __restrict__ Q, const float* __restrict__ K,
    const float* __restrict__ V, float* __restrict__ Out) {
  __shared__ ushort_t K_sh[64 * 128];
  __shared__ ushort_t V_sh[128 * 64];
  __shared__ ushort_t P_sh[4][16 * 64];

  const int tid  = threadIdx.x;
  const int lane = tid & 63;
  const int wv   = tid >> 6;
  const int l16  = lane & 15;
  const int lhi  = lane >> 4;
  const int qblk = blockIdx.x;
  const int bh   = blockIdx.y;
  const float scale = 0.08838834764831845f;

  const size_t base = (size_t)bh * SLEN * DDIM;
  const float* Qp = Q + base;
  const float* Kp = K + base;
  const float* Vp = V + base;
  float*       Op = Out + base;

  bf16x8 qf[4];
  {
    const int qrow = qblk * 64 + wv * 16 + l16;
    const float* qr = Qp + (size_t)qrow * DDIM;
#pragma unroll
    for (int dc = 0; dc < 4; ++dc) {
      int d0 = dc * 32 + lhi * 8;
      float4 x = *reinterpret_cast<const float4*>(qr + d0);
      float4 y = *reinterpret_cast<const float4*>(qr + d0 + 4);
      ushort8 uu;
      uu[0] = f2bf(x.x * scale); uu[1] = f2bf(x.y * scale);
      uu[2] = f2bf(x.z * scale); uu[3] = f2bf(x.w * scale);
      uu[4] = f2bf(y.x * scale); uu[5] = f2bf(y.y * scale);
      uu[6] = f2bf(y.z * scale); uu[7] = f2bf(y.w * scale);
      qf[dc] = __builtin_bit_cast(bf16x8, uu);
    }
  }

  f32x4 Oacc[8];
#pragma unroll
  for (int i = 0; i < 8; ++i) Oacc[i] = (f32x4){0.f, 0.f, 0.f, 0.f};
  float m_run[4], l_run[4];
#pragma unroll
  for (int r = 0; r < 4; ++r) { m_run[r] = -3.0e38f; l_run[r] = 0.f; }

  for (int kb = 0; kb <= qblk; ++kb) {
    __syncthreads();
    {
      const float* src = Kp + (size_t)kb * 64 * DDIM;
#pragma unroll
      for (int it = 0; it < 8; ++it) {
        int idx4 = it * 256 + tid;
        int r  = idx4 >> 5;
        int c4 = idx4 & 31;
        float4 x = *reinterpret_cast<const float4*>(src + r * DDIM + c4 * 4);
        unsigned lo = ((unsigned)f2bf(x.y) << 16) | f2bf(x.x);
        unsigned hh = ((unsigned)f2bf(x.w) << 16) | f2bf(x.z);
        int e = (r * 128 + c4 * 4) ^ ((r & 7) << 3);
        *reinterpret_cast<uint2*>(&K_sh[e]) = make_uint2(lo, hh);
      }
      const float* vs = Vp + (size_t)kb * 64 * DDIM;
#pragma unroll
      for (int it = 0; it < 8; ++it) {
        int idx4 = it * 256 + tid;
        int r  = idx4 >> 5;
        int c4 = idx4 & 31;
        float4 x = *reinterpret_cast<const float4*>(vs + r * DDIM + c4 * 4);
        int c0 = c4 * 4;
        float vals[4] = {x.x, x.y, x.z, x.w};
#pragma unroll
        for (int j = 0; j < 4; ++j) {
          int d = c0 + j;
          V_sh[(d * 64 + r) ^ ((d & 7) << 3)] = f2bf(vals[j]);
        }
      }
    }
    __syncthreads();

    f32x4 sacc[4];
#pragma unroll
    for (int g = 0; g < 4; ++g) {
      f32x4 acc = (f32x4){0.f, 0.f, 0.f, 0.f};
#pragma unroll
      for (int dc = 0; dc < 4; ++dc) {
        int row = g * 16 + l16;
        int e = (row * 128 + dc * 32 + lhi * 8) ^ ((row & 7) << 3);
        bf16x8 kf = *reinterpret_cast<const bf16x8*>(&K_sh[e]);
        acc = __builtin_amdgcn_mfma_f32_16x16x32_bf16(qf[dc], kf, acc, 0, 0, 0);
      }
      sacc[g] = acc;
    }

    if (kb == qblk) {
      int q0 = lhi * 4;
#pragma unroll
      for (int g = 0; g < 4; ++g) {
        int kcol = g * 16 + l16;
#pragma unroll
        for (int r = 0; r < 4; ++r) {
          if (kcol > wv * 16 + q0 + r) sacc[g][r] = -3.0e38f;
        }
      }
    }

    float tmax[4];
#pragma unroll
    for (int r = 0; r < 4; ++r)
      tmax[r] = fmaxf(fmaxf(sacc[0][r], sacc[1][r]),
                      fmaxf(sacc[2][r], sacc[3][r]));
#pragma unroll
    for (int x = 1; x < 16; x <<= 1) {
#pragma unroll
      for (int r = 0; r < 4; ++r)
        tmax[r] = fmaxf(tmax[r], __shfl_xor(tmax[r], x));
    }

    float alpha[4], mnew[4];
#pragma unroll
    for (int r = 0; r < 4; ++r) {
      mnew[r]  = fmaxf(m_run[r], tmax[r]);
      alpha[r] = __expf(m_run[r] - mnew[r]);
      m_run[r] = mnew[r];
    }

    float rsum[4] = {0.f, 0.f, 0.f, 0.f};
#pragma unroll
    for (int g = 0; g < 4; ++g) {
#pragma unroll
      for (int r = 0; r < 4; ++r) {
        float p = __expf(sacc[g][r] - mnew[r]);
        rsum[r] += p;
        int prow = lhi * 4 + r;
        P_sh[wv][(prow * 64 + g * 16 + l16) ^ ((prow & 7) << 3)] = f2bf(p);
      }
    }
#pragma unroll
    for (int x = 1; x < 16; x <<= 1) {
#pragma unroll
      for (int r = 0; r < 4; ++r) rsum[r] += __shfl_xor(rsum[r], x);
    }
#pragma unroll
    for (int r = 0; r < 4; ++r) l_run[r] = l_run[r] * alpha[r] + rsum[r];

#pragma unroll
    for (int dg = 0; dg < 8; ++dg)
#pragma unroll
      for (int r = 0; r < 4; ++r) Oacc[dg][r] *= alpha[r];

    bf16x8 pf[2];
#pragma unroll
    for (int kc = 0; kc < 2; ++kc) {
      int e = (l16 * 64 + kc * 32 + lhi * 8) ^ ((l16 & 7) << 3);
      pf[kc] = *reinterpret_cast<const bf16x8*>(&P_sh[wv][e]);
    }
#pragma unroll
    for (int dg = 0; dg < 8; ++dg) {
#pragma unroll
      for (int kc = 0; kc < 2; ++kc) {
        int row = dg * 16 + l16;
        int e = (row * 64 + kc * 32 + lhi * 8) ^ ((row & 7) << 3);
        bf16x8 vf = *reinterpret_cast<const bf16x8*>(&V_sh[e]);
        Oacc[dg] = __builtin_amdgcn_mfma_f32_16x16x32_bf16(pf[kc], vf, Oacc[dg], 0, 0, 0);
      }
    }
  }

#pragma unroll
  for (int r = 0; r < 4; ++r) {
    float inv = 1.0f / l_run[r];
    int q = qblk * 64 + wv * 16 + lhi * 4 + r;
    float* orow = Op + (size_t)q * DDIM;
#pragma unroll
    for (int dg = 0; dg < 8; ++dg)
      orow[dg * 16 + l16] = Oacc[dg][r] * inv;
  }
}

extern "C" void kernel_launch(void* const* d_in, const int* in_sizes, int n_in,
                              void* d_out, int out_size, void* d_ws, size_t ws_size,
                              hipStream_t stream) {
  const float* Q = (const float*)d_in[0];
  const float* K = (const float*)d_in[1];
  const float* V = (const float*)d_in[2];
  float* O = (float*)d_out;

  const size_t n_elem = (size_t)NBH * SLEN * DDIM;   // 16,777,216
  const size_t need   = n_elem * 2 * 2;              // Kb + Vt bf16

  if (ws_size >= need) {
    ushort_t* Kbf = (ushort_t*)d_ws;
    ushort_t* Vt  = Kbf + n_elem;
    convert_k_kernel<<<2048, 256, 0, stream>>>(K, Kbf, (int)(n_elem / 4));
    transpose_v_kernel<<<dim3(SLEN / 64, DDIM / 32, NBH), 256, 0, stream>>>(V, Vt);
    fattn3_kernel<<<dim3(SLEN / QB, NBH), dim3(512), 0, stream>>>(Q, Kbf, Vt, O);
  } else {
    fattn_kernel<<<dim3(SLEN / 64, NBH), dim3(256), 0, stream>>>(Q, K, V, O);
  }
}

// Round 4
// 143.100 us; speedup vs baseline: 5.2756x; 1.0468x over previous
//
#include <hip/hip_runtime.h>

// Flash-attention forward, causal, B=4 H=16 S=2048 D=128, fp32 in/out.
// Round 4: VALU-diet on the 8-wave 32x32 structure:
//   - exp2-domain softmax (log2e folded into Q prescale): p = v_exp_f32(s-m)
//   - defer-max (T13, THR=11 log2): skip O-rescale when max growth small
//   - P^T fragment exchange via v_permlane32_swap_b32 (T12) - no cndmask/bpermute
//   - 4-way partial max/sum reductions (chain depth 32 -> 8)
//   - s_setprio(1) around MFMA clusters (T5)

#define SLEN 2048
#define DDIM 128
#define NBH  64
#define QB   256
#define KB   64

typedef __bf16 bf16x8 __attribute__((ext_vector_type(8)));
typedef float  f32x16 __attribute__((ext_vector_type(16)));
typedef float  f32x4  __attribute__((ext_vector_type(4)));
typedef unsigned uint32x4 __attribute__((ext_vector_type(4)));
typedef unsigned short ushort_t;
typedef ushort_t ushort8 __attribute__((ext_vector_type(8)));

__device__ inline ushort_t f2bf(float f) {
  union { float f; unsigned u; } v; v.f = f;
  unsigned u = v.u;
  u += 0x7FFFu + ((u >> 16) & 1u);   // RNE, finite inputs only
  return (ushort_t)(u >> 16);
}

__device__ inline unsigned cvtpk_bf16(float lo, float hi) {
  unsigned r;
  asm("v_cvt_pk_bf16_f32 %0, %1, %2" : "=v"(r) : "v"(lo), "v"(hi));
  return r;
}

__device__ inline float exp2_fast(float x) {
  float r;
  asm("v_exp_f32 %0, %1" : "=v"(r) : "v"(x));
  return r;
}

// ---------------- pre-pass: K fp32 -> bf16 (same layout) ----------------
__global__ __launch_bounds__(256) void convert_k_kernel(
    const float* __restrict__ in, ushort_t* __restrict__ out, int n4) {
  int stride = gridDim.x * blockDim.x;
  for (int i = blockIdx.x * blockDim.x + threadIdx.x; i < n4; i += stride) {
    float4 x = reinterpret_cast<const float4*>(in)[i];
    unsigned lo = (unsigned)f2bf(x.x) | ((unsigned)f2bf(x.y) << 16);
    unsigned hi = (unsigned)f2bf(x.z) | ((unsigned)f2bf(x.w) << 16);
    reinterpret_cast<uint2*>(out)[i] = make_uint2(lo, hi);
  }
}

// ------------- pre-pass: V [bh][s][d] fp32 -> Vt [bh][d][s] bf16 -------------
__global__ __launch_bounds__(256) void transpose_v_kernel(
    const float* __restrict__ V, ushort_t* __restrict__ Vt) {
  __shared__ float t[64][33];
  const int bh = blockIdx.z;
  const int s0 = blockIdx.x * 64;
  const int d0 = blockIdx.y * 32;
  const int tx = threadIdx.x & 31;
  const int ty = threadIdx.x >> 5;
  const float* src = V + ((size_t)bh * SLEN + s0) * DDIM + d0;
#pragma unroll
  for (int j = 0; j < 8; ++j) {
    int sl = ty + j * 8;
    t[sl][tx] = src[(size_t)sl * DDIM + tx];
  }
  __syncthreads();
  ushort_t* dst = Vt + ((size_t)bh * DDIM + d0) * SLEN + s0;
#pragma unroll
  for (int j = 0; j < 4; ++j) {
    int dl = ty + j * 8;
    unsigned lo = f2bf(t[tx * 2][dl]);
    unsigned hi = f2bf(t[tx * 2 + 1][dl]);
    *reinterpret_cast<unsigned*>(&dst[(size_t)dl * SLEN + tx * 2]) =
        lo | (hi << 16);
  }
}

// ---------------- main kernel: 8 waves, 32x32 MFMA ----------------
__global__ __launch_bounds__(512, 2) void fattn4_kernel(
    const float* __restrict__ Q, const ushort_t* __restrict__ Kb,
    const ushort_t* __restrict__ Vt, float* __restrict__ Out) {
  __shared__ ushort_t K_sh[2][KB * DDIM];   // [buf][k][d]  16KB each
  __shared__ ushort_t V_sh[2][DDIM * KB];   // [buf][d][k]  16KB each

  const int tid  = threadIdx.x;
  const int lane = tid & 63;
  const int wv   = tid >> 6;         // 0..7
  const int l31  = lane & 31;
  const int hi   = lane >> 5;        // 0/1
  // heavy/light pairing: paired WGs sum to exactly 36 tile-units
  const int qblk = (blockIdx.y >= 32) ? blockIdx.x : (7 - (int)blockIdx.x);
  const int bh   = blockIdx.y;

  // 1/sqrt(128) * log2(e): softmax runs in exp2 domain
  const float qscale = 0.12751744f;
  const float THR = 11.0f;           // defer-max threshold (log2 units)

  const float*    Qp = Q  + (size_t)bh * SLEN * DDIM;
  const ushort_t* Kp = Kb + (size_t)bh * SLEN * DDIM;
  const ushort_t* Vp = Vt + (size_t)bh * DDIM * SLEN;
  float*          Op = Out + (size_t)bh * SLEN * DDIM;

  const int q0w = qblk * QB + wv * 32;   // wave's first q row
  const int qg  = q0w + l31;             // this lane's q row

  // ---- Q fragments: B-operand of S^T = K·Q^T. B[d=hi*8+i+16*ds][q=l31] ----
  bf16x8 qf[8];
  {
    const float* qr = Qp + (size_t)qg * DDIM;
#pragma unroll
    for (int ds = 0; ds < 8; ++ds) {
      int d0 = ds * 16 + hi * 8;
      float4 x = *reinterpret_cast<const float4*>(qr + d0);
      float4 y = *reinterpret_cast<const float4*>(qr + d0 + 4);
      ushort8 uu;
      uu[0] = f2bf(x.x * qscale); uu[1] = f2bf(x.y * qscale);
      uu[2] = f2bf(x.z * qscale); uu[3] = f2bf(x.w * qscale);
      uu[4] = f2bf(y.x * qscale); uu[5] = f2bf(y.y * qscale);
      uu[6] = f2bf(y.z * qscale); uu[7] = f2bf(y.w * qscale);
      qf[ds] = __builtin_bit_cast(bf16x8, uu);
    }
  }

  f32x16 Oacc[4];   // O^T tiles: row=d_local (reg-mapped), col=q (lane-local)
#pragma unroll
  for (int dt = 0; dt < 4; ++dt)
#pragma unroll
    for (int r = 0; r < 16; ++r) Oacc[dt][r] = 0.f;
  float m_run = -3.0e38f, l_run = 0.f;

  const int last_kb      = qblk * 4 + 3;         // WG-uniform tile count
  const int last_kb_wave = (q0w + 31) >> 6;      // beyond: wave skips compute

  auto stage = [&](int buf, int kb) {
    const ushort_t* ksrc = Kp + (size_t)kb * KB * DDIM;
#pragma unroll
    for (int j = 0; j < 2; ++j) {
      int chunk = wv * 128 + j * 64 + lane;      // 16B chunk id, 1024 total
      int row = chunk >> 4, c = chunk & 15;
      const ushort_t* g = ksrc + row * DDIM + ((c ^ (row & 7)) << 3);
      ushort_t* l = &K_sh[buf][(size_t)(wv * 128 + j * 64) * 8];
      __builtin_amdgcn_global_load_lds(
          (const __attribute__((address_space(1))) unsigned*)g,
          (__attribute__((address_space(3))) unsigned*)l, 16, 0, 0);
    }
    const ushort_t* vsrc = Vp + (size_t)kb * KB;
#pragma unroll
    for (int j = 0; j < 2; ++j) {
      int chunk = wv * 128 + j * 64 + lane;      // 1024 chunks of V^T tile
      int row = chunk >> 3, c = chunk & 7;
      const ushort_t* g = vsrc + (size_t)row * SLEN + ((c ^ (row & 7)) << 3);
      ushort_t* l = &V_sh[buf][(size_t)(wv * 128 + j * 64) * 8];
      __builtin_amdgcn_global_load_lds(
          (const __attribute__((address_space(1))) unsigned*)g,
          (__attribute__((address_space(3))) unsigned*)l, 16, 0, 0);
    }
  };

  stage(0, 0);

  for (int kb = 0; kb <= last_kb; ++kb) {
    __syncthreads();                 // drains vmcnt: tile kb resident
    if (kb < last_kb) stage((kb + 1) & 1, kb + 1);  // in flight under compute

    if (kb <= last_kb_wave) {
      const int buf = kb & 1;

      // ---- S^T = K·Q^T : C col = q (lane-local), row = key ----
      f32x16 sac[2];
#pragma unroll
      for (int mt = 0; mt < 2; ++mt) {
        f32x16 a;
#pragma unroll
        for (int r = 0; r < 16; ++r) a[r] = 0.f;
        int row = mt * 32 + l31;
        int sw = row & 7;
        __builtin_amdgcn_s_setprio(1);
#pragma unroll
        for (int ds = 0; ds < 8; ++ds) {
          int c = ds * 2 + hi;
          bf16x8 kf = *reinterpret_cast<const bf16x8*>(
              &K_sh[buf][row * DDIM + ((c ^ sw) << 3)]);
          a = __builtin_amdgcn_mfma_f32_32x32x16_bf16(kf, qf[ds], a, 0, 0, 0);
        }
        __builtin_amdgcn_s_setprio(0);
        sac[mt] = a;
      }

      // ---- causal mask (only tiles that can cross the diagonal) ----
      if (kb * 64 + 63 > q0w) {
#pragma unroll
        for (int mt = 0; mt < 2; ++mt) {
          int kbase = kb * 64 + mt * 32 + 4 * hi;
#pragma unroll
          for (int r = 0; r < 16; ++r) {
            int krow = (r & 3) + 8 * (r >> 2);
            if (kbase + krow > qg) sac[mt][r] = -3.0e38f;
          }
        }
      }

      // ---- tile max: 4-way partial chains, then combine ----
      float p0 = sac[0][0], p1 = sac[0][1], p2 = sac[0][2], p3 = sac[0][3];
#pragma unroll
      for (int r = 4; r < 16; r += 4) {
        p0 = fmaxf(p0, sac[0][r + 0]); p1 = fmaxf(p1, sac[0][r + 1]);
        p2 = fmaxf(p2, sac[0][r + 2]); p3 = fmaxf(p3, sac[0][r + 3]);
      }
#pragma unroll
      for (int r = 0; r < 16; r += 4) {
        p0 = fmaxf(p0, sac[1][r + 0]); p1 = fmaxf(p1, sac[1][r + 1]);
        p2 = fmaxf(p2, sac[1][r + 2]); p3 = fmaxf(p3, sac[1][r + 3]);
      }
      float tm = fmaxf(fmaxf(p0, p1), fmaxf(p2, p3));
      tm = fmaxf(tm, __shfl_xor(tm, 32));

      // ---- defer-max: only rescale when max grew past THR ----
      if (!__all(tm - m_run <= THR)) {
        float mnew  = fmaxf(m_run, tm);
        float alpha = exp2_fast(m_run - mnew);
        m_run = mnew;
        l_run *= alpha;
#pragma unroll
        for (int dt = 0; dt < 4; ++dt)
#pragma unroll
          for (int r = 0; r < 16; ++r) Oacc[dt][r] *= alpha;
      }

      // ---- P = exp2(S - m), 4-way partial sums ----
      float s0 = 0.f, s1 = 0.f, s2 = 0.f, s3 = 0.f;
#pragma unroll
      for (int mt = 0; mt < 2; ++mt)
#pragma unroll
        for (int r = 0; r < 16; r += 4) {
          float e0 = exp2_fast(sac[mt][r + 0] - m_run);
          float e1 = exp2_fast(sac[mt][r + 1] - m_run);
          float e2 = exp2_fast(sac[mt][r + 2] - m_run);
          float e3 = exp2_fast(sac[mt][r + 3] - m_run);
          sac[mt][r + 0] = e0; sac[mt][r + 1] = e1;
          sac[mt][r + 2] = e2; sac[mt][r + 3] = e3;
          s0 += e0; s1 += e1; s2 += e2; s3 += e3;
        }
      float rs = (s0 + s1) + (s2 + s3);
      rs += __shfl_xor(rs, 32);
      l_run += rs;

      // ---- P^T fragments: cvt_pk + permlane32_swap (T12) ----
      uint32x4 pw[4];
#pragma unroll
      for (int ks = 0; ks < 4; ++ks) {
        const int mt = ks >> 1;
        const int hb = 8 * (ks & 1);
        unsigned X  = cvtpk_bf16(sac[mt][hb + 0], sac[mt][hb + 1]);
        unsigned X2 = cvtpk_bf16(sac[mt][hb + 2], sac[mt][hb + 3]);
        unsigned Y  = cvtpk_bf16(sac[mt][hb + 4], sac[mt][hb + 5]);
        unsigned Y2 = cvtpk_bf16(sac[mt][hb + 6], sac[mt][hb + 7]);
        asm("v_permlane32_swap_b32 %0, %1" : "+v"(X),  "+v"(Y));
        asm("v_permlane32_swap_b32 %0, %1" : "+v"(X2), "+v"(Y2));
        uint32x4 f; f.x = X; f.y = X2; f.z = Y; f.w = Y2;
        pw[ks] = f;
      }

      // ---- O^T += V^T · P^T ----
#pragma unroll
      for (int dt = 0; dt < 4; ++dt) {
        int row = dt * 32 + l31;
        int sw = row & 7;
        __builtin_amdgcn_s_setprio(1);
#pragma unroll
        for (int ks = 0; ks < 4; ++ks) {
          int c = ks * 2 + hi;
          bf16x8 vf = *reinterpret_cast<const bf16x8*>(
              &V_sh[buf][row * 64 + ((c ^ sw) << 3)]);
          Oacc[dt] = __builtin_amdgcn_mfma_f32_32x32x16_bf16(
              vf, __builtin_bit_cast(bf16x8, pw[ks]), Oacc[dt], 0, 0, 0);
        }
        __builtin_amdgcn_s_setprio(0);
      }
    }
  }

  // ---- epilogue: O[q][d] = O^T normalized ----
  {
    float invl = 1.0f / l_run;
    float* orow = Op + (size_t)qg * DDIM;
#pragma unroll
    for (int dt = 0; dt < 4; ++dt)
#pragma unroll
      for (int r = 0; r < 16; ++r) {
        int d = dt * 32 + (r & 3) + 8 * (r >> 2) + 4 * hi;
        orow[d] = Oacc[dt][r] * invl;
      }
  }
}

// ---------------- fallback (round-1 fp32-direct kernel) ----------------
__global__ __launch_bounds__(256) void fattn_kernel(
    const float* __restrict__ Q, const float* __restrict__ K,
    const float* __restrict__ V, float* __restrict__ Out) {
  __shared__ ushort_t K_sh[64 * 128];
  __shared__ ushort_t V_sh[128 * 64];
  __shared__ ushort_t P_sh[4][16 * 64];

  const int tid  = threadIdx.x;
  const int lane = tid & 63;
  const int wv   = tid >> 6;
  const int l16  = lane & 15;
  const int lhi  = lane >> 4;
  const int qblk = blockIdx.x;
  const int bh   = blockIdx.y;
  const float scale = 0.08838834764831845f;

  const size_t base = (size_t)bh * SLEN * DDIM;
  const float* Qp = Q + base;
  const float* Kp = K + base;
  const float* Vp = V + base;
  float*       Op = Out + base;

  bf16x8 qf[4];
  {
    const int qrow = qblk * 64 + wv * 16 + l16;
    const float* qr = Qp + (size_t)qrow * DDIM;
#pragma unroll
    for (int dc = 0; dc < 4; ++dc) {
      int d0 = dc * 32 + lhi * 8;
      float4 x = *reinterpret_cast<const float4*>(qr + d0);
      float4 y = *reinterpret_cast<const float4*>(qr + d0 + 4);
      ushort8 uu;
      uu[0] = f2bf(x.x * scale); uu[1] = f2bf(x.y * scale);
      uu[2] = f2bf(x.z * scale); uu[3] = f2bf(x.w * scale);
      uu[4] = f2bf(y.x * scale); uu[5] = f2bf(y.y * scale);
      uu[6] = f2bf(y.z * scale); uu[7] = f2bf(y.w * scale);
      qf[dc] = __builtin_bit_cast(bf16x8, uu);
    }
  }

  f32x4 Oacc[8];
#pragma unroll
  for (int i = 0; i < 8; ++i) Oacc[i] = (f32x4){0.f, 0.f, 0.f, 0.f};
  float m_run[4], l_run[4];
#pragma unroll
  for (int r = 0; r < 4; ++r) { m_run[r] = -3.0e38f; l_run[r] = 0.f; }

  for (int kb = 0; kb <= qblk; ++kb) {
    __syncthreads();
    {
      const float* src = Kp + (size_t)kb * 64 * DDIM;
#pragma unroll
      for (int it = 0; it < 8; ++it) {
        int idx4 = it * 256 + tid;
        int r  = idx4 >> 5;
        int c4 = idx4 & 31;
        float4 x = *reinterpret_cast<const float4*>(src + r * DDIM + c4 * 4);
        unsigned lo = ((unsigned)f2bf(x.y) << 16) | f2bf(x.x);
        unsigned hh = ((unsigned)f2bf(x.w) << 16) | f2bf(x.z);
        int e = (r * 128 + c4 * 4) ^ ((r & 7) << 3);
        *reinterpret_cast<uint2*>(&K_sh[e]) = make_uint2(lo, hh);
      }
      const float* vs = Vp + (size_t)kb * 64 * DDIM;
#pragma unroll
      for (int it = 0; it < 8; ++it) {
        int idx4 = it * 256 + tid;
        int r  = idx4 >> 5;
        int c4 = idx4 & 31;
        float4 x = *reinterpret_cast<const float4*>(vs + r * DDIM + c4 * 4);
        int c0 = c4 * 4;
        float vals[4] = {x.x, x.y, x.z, x.w};
#pragma unroll
        for (int j = 0; j < 4; ++j) {
          int d = c0 + j;
          V_sh[(d * 64 + r) ^ ((d & 7) << 3)] = f2bf(vals[j]);
        }
      }
    }
    __syncthreads();

    f32x4 sacc[4];
#pragma unroll
    for (int g = 0; g < 4; ++g) {
      f32x4 acc = (f32x4){0.f, 0.f, 0.f, 0.f};
#pragma unroll
      for (int dc = 0; dc < 4; ++dc) {
        int row = g * 16 + l16;
        int e = (row * 128 + dc * 32 + lhi * 8) ^ ((row & 7) << 3);
        bf16x8 kf = *reinterpret_cast<const bf16x8*>(&K_sh[e]);
        acc = __builtin_amdgcn_mfma_f32_16x16x32_bf16(qf[dc], kf, acc, 0, 0, 0);
      }
      sacc[g] = acc;
    }

    if (kb == qblk) {
      int q0 = lhi * 4;
#pragma unroll
      for (int g = 0; g < 4; ++g) {
        int kcol = g * 16 + l16;
#pragma unroll
        for (int r = 0; r < 4; ++r) {
          if (kcol > wv * 16 + q0 + r) sacc[g][r] = -3.0e38f;
        }
      }
    }

    float tmax[4];
#pragma unroll
    for (int r = 0; r < 4; ++r)
      tmax[r] = fmaxf(fmaxf(sacc[0][r], sacc[1][r]),
                      fmaxf(sacc[2][r], sacc[3][r]));
#pragma unroll
    for (int x = 1; x < 16; x <<= 1) {
#pragma unroll
      for (int r = 0; r < 4; ++r)
        tmax[r] = fmaxf(tmax[r], __shfl_xor(tmax[r], x));
    }

    float alpha[4], mnew[4];
#pragma unroll
    for (int r = 0; r < 4; ++r) {
      mnew[r]  = fmaxf(m_run[r], tmax[r]);
      alpha[r] = __expf(m_run[r] - mnew[r]);
      m_run[r] = mnew[r];
    }

    float rsum[4] = {0.f, 0.f, 0.f, 0.f};
#pragma unroll
    for (int g = 0; g < 4; ++g) {
#pragma unroll
      for (int r = 0; r < 4; ++r) {
        float p = __expf(sacc[g][r] - mnew[r]);
        rsum[r] += p;
        int prow = lhi * 4 + r;
        P_sh[wv][(prow * 64 + g * 16 + l16) ^ ((prow & 7) << 3)] = f2bf(p);
      }
    }
#pragma unroll
    for (int x = 1; x < 16; x <<= 1) {
#pragma unroll
      for (int r = 0; r < 4; ++r) rsum[r] += __shfl_xor(rsum[r], x);
    }
#pragma unroll
    for (int r = 0; r < 4; ++r) l_run[r] = l_run[r] * alpha[r] + rsum[r];

#pragma unroll
    for (int dg = 0; dg < 8; ++dg)
#pragma unroll
      for (int r = 0; r < 4; ++r) Oacc[dg][r] *= alpha[r];

    bf16x8 pf[2];
#pragma unroll
    for (int kc = 0; kc < 2; ++kc) {
      int e = (l16 * 64 + kc * 32 + lhi * 8) ^ ((l16 & 7) << 3);
      pf[kc] = *reinterpret_cast<const bf16x8*>(&P_sh[wv][e]);
    }
#pragma unroll
    for (int dg = 0; dg < 8; ++dg) {
#pragma unroll
      for (int kc = 0; kc < 2; ++kc) {
        int row = dg * 16 + l16;
        int e = (row * 64 + kc * 32 + lhi * 8) ^ ((row & 7) << 3);
        bf16x8 vf = *reinterpret_cast<const bf16x8*>(&V_sh[e]);
        Oacc[dg] = __builtin_amdgcn_mfma_f32_16x16x32_bf16(pf[kc], vf, Oacc[dg], 0, 0, 0);
      }
    }
  }

#pragma unroll
  for (int r = 0; r < 4; ++r) {
    float inv = 1.0f / l_run[r];
    int q = qblk * 64 + wv * 16 + lhi * 4 + r;
    float* orow = Op + (size_t)q * DDIM;
#pragma unroll
    for (int dg = 0; dg < 8; ++dg)
      orow[dg * 16 + l16] = Oacc[dg][r] * inv;
  }
}

extern "C" void kernel_launch(void* const* d_in, const int* in_sizes, int n_in,
                              void* d_out, int out_size, void* d_ws, size_t ws_size,
                              hipStream_t stream) {
  const float* Q = (const float*)d_in[0];
  const float* K = (const float*)d_in[1];
  const float* V = (const float*)d_in[2];
  float* O = (float*)d_out;

  const size_t n_elem = (size_t)NBH * SLEN * DDIM;   // 16,777,216
  const size_t need   = n_elem * 2 * 2;              // Kb + Vt bf16

  if (ws_size >= need) {
    ushort_t* Kbf = (ushort_t*)d_ws;
    ushort_t* Vt  = Kbf + n_elem;
    convert_k_kernel<<<2048, 256, 0, stream>>>(K, Kbf, (int)(n_elem / 4));
    transpose_v_kernel<<<dim3(SLEN / 64, DDIM / 32, NBH), 256, 0, stream>>>(V, Vt);
    fattn4_kernel<<<dim3(SLEN / QB, NBH), dim3(512), 0, stream>>>(Q, Kbf, Vt, O);
  } else {
    fattn_kernel<<<dim3(SLEN / 64, NBH), dim3(256), 0, stream>>>(Q, K, V, O);
  }
}